// Round 17
// baseline (79.135 us; speedup 1.0000x reference)
//
#include <hip/hip_runtime.h>
#include <hip/hip_bf16.h>

#define NB 2
#define ND 256
#define NE 2048
#define NH 4
#define MAXP 8
#define PSTR8 2064   // LDS P row stride (bytes)

typedef __attribute__((ext_vector_type(8))) short bf16x8;
typedef __attribute__((ext_vector_type(4))) float f32x4;

static __device__ __forceinline__ short f2b(float f) {
    union { __hip_bfloat16 h; short s; } u;
    u.h = __float2bfloat16(f);
    return u.s;
}

static __device__ __forceinline__ f32x4 mfma16(bf16x8 a, bf16x8 b, f32x4 c) {
    return __builtin_amdgcn_mfma_f32_16x16x32_bf16(a, b, c, 0, 0, 0);
}

static __device__ __forceinline__ f32x4 mfma8(long long a, long long b, f32x4 c) {
    return __builtin_amdgcn_mfma_f32_16x16x32_fp8_fp8(a, b, c, 0, 0, 0);
}

static __device__ __forceinline__ unsigned char f2fp8(float f) {
    return (unsigned char)(__builtin_amdgcn_cvt_pk_fp8_f32(f, 0.f, 0, false) & 0xFF);
}

// ---------------- front: d8 pack (blk<256) | weight cvt (256..383) | prep (384..447) --
__global__ __launch_bounds__(512) void k_front(const int* __restrict__ dist,
        unsigned char* __restrict__ d8p,
        const float* __restrict__ w_qs, const float* __restrict__ w_ks,
        const float* __restrict__ w_vs, const float* __restrict__ w_fc,
        short* __restrict__ wqsb, short* __restrict__ wksb,
        short* __restrict__ wvsb, short* __restrict__ wfcb,
        const float* __restrict__ x, const float* __restrict__ g_,
        const float* __restrict__ bb, short* __restrict__ sbf,
        short* __restrict__ qnb) {
    __shared__ __align__(16) char fbuf[33024];
    int blk = blockIdx.x;
    int t = threadIdx.x;
    if (blk < 256) {
        unsigned char (*L)[2064] = (unsigned char (*)[2064])fbuf;
        int b = blk >> 7, strip = blk & 127;
        const int* base = dist + ((size_t)b * NE + strip * 16) * NE;
        #pragma unroll
        for (int row = 0; row < 16; row++) {
            int4 v = *(const int4*)&base[(size_t)row * NE + t * 4];
            uchar4 o;
            o.x = (unsigned char)(v.x < 9 ? v.x : 9);
            o.y = (unsigned char)(v.y < 9 ? v.y : 9);
            o.z = (unsigned char)(v.z < 9 ? v.z : 9);
            o.w = (unsigned char)(v.w < 9 ? v.w : 9);
            *(uchar4*)&L[row][t * 4] = o;
        }
        __syncthreads();
        unsigned char* out = d8p + ((size_t)(b * 128 + strip)) * 32768;
        #pragma unroll
        for (int i = 0; i < 16; i++) {
            int w = i * 512 + t;
            int colblk = w >> 8;
            int rem = w & 255;
            int c = rem >> 6, lane6 = rem & 63;
            int g = lane6 >> 4, l16 = lane6 & 15;
            uchar4 val = *(const uchar4*)&L[l16][colblk * 64 + c * 16 + g * 4];
            *(uchar4*)&out[(size_t)w * 4] = val;
        }
    } else if (blk < 384) {
        int i = (blk - 256) * 512 + t;
        int which = i >> 14;
        int idx = i & 16383;
        const float* in = which == 0 ? w_qs : which == 1 ? w_ks : which == 2 ? w_vs : w_fc;
        short* out = which == 0 ? wqsb : which == 1 ? wksb : which == 2 ? wvsb : wfcb;
        f32x4 v = ((const f32x4*)in)[idx];
        short4 o;
        o.x = f2b(v[0]); o.y = f2b(v[1]); o.z = f2b(v[2]); o.w = f2b(v[3]);
        ((short4*)out)[idx] = o;
    } else {
        float (*tileT)[257] = (float (*)[257])fbuf;
        int blk2 = blk - 384;
        int b = blk2 >> 6;
        int e0 = (blk2 & 63) * 32;
        int tx = t & 31, ty = t >> 5;
        #pragma unroll
        for (int d0 = 0; d0 < 256; d0 += 32) {
            #pragma unroll
            for (int r = 0; r < 2; r++) {
                int dd = d0 + ty + r * 16;
                tileT[tx][dd] = x[((size_t)b * ND + dd) * NE + e0 + tx];
            }
        }
        __syncthreads();
        int wave = t >> 6, lane = t & 63;
        #pragma unroll 1
        for (int rr = 0; rr < 4; rr++) {
            int e = wave * 4 + rr;
            float v0 = tileT[e][lane], v1 = tileT[e][lane + 64];
            float v2 = tileT[e][lane + 128], v3 = tileT[e][lane + 192];
            float sum = (v0 + v1) + (v2 + v3);
            #pragma unroll
            for (int off = 32; off; off >>= 1) sum += __shfl_xor(sum, off);
            float mean = sum * (1.0f / ND);
            float d0 = v0 - mean, d1 = v1 - mean, d2 = v2 - mean, d3 = v3 - mean;
            float sq = (d0 * d0 + d1 * d1) + (d2 * d2 + d3 * d3);
            #pragma unroll
            for (int off = 32; off; off >>= 1) sq += __shfl_xor(sq, off);
            float inv = rsqrtf(sq * (1.0f / ND) + 1e-6f);
            size_t base = ((size_t)b * NE + e0 + e) * ND;
            sbf[base + lane]       = f2b(v0);
            sbf[base + lane + 64]  = f2b(v1);
            sbf[base + lane + 128] = f2b(v2);
            sbf[base + lane + 192] = f2b(v3);
            qnb[base + lane]       = f2b(d0 * inv * g_[lane]       + bb[lane]);
            qnb[base + lane + 64]  = f2b(d1 * inv * g_[lane + 64]  + bb[lane + 64]);
            qnb[base + lane + 128] = f2b(d2 * inv * g_[lane + 128] + bb[lane + 128]);
            qnb[base + lane + 192] = f2b(d3 * inv * g_[lane + 192] + bb[lane + 192]);
        }
    }
}

// ---------------- merged QKV MFMA GEMM ----------------
__global__ __launch_bounds__(256) void k_gemm_qkv(const short* __restrict__ qnb,
        const short* __restrict__ sbf, const short* __restrict__ wq,
        const short* __restrict__ wk, const short* __restrict__ wv,
        const float* __restrict__ w_rpr, unsigned char* __restrict__ qf8,
        unsigned char* __restrict__ kp8, unsigned char* __restrict__ vp8,
        uint4* __restrict__ qdrT8) {
    int z = blockIdx.z;
    const short* A = z == 0 ? qnb : sbf;
    const short* W = z == 0 ? wq : z == 1 ? wk : wv;
    int t = threadIdx.x;
    int wv_ = t >> 6, lane = t & 63;
    int l16 = lane & 15, g = lane >> 4, lk = g * 8;
    int m0 = blockIdx.x * 64;
    int h = blockIdx.y;
    int n0 = h * 64;
    int mw = m0 + wv_ * 16;
    const short* Ab = A + (size_t)(mw + l16) * 256 + lk;
    const short* Wb = W + (size_t)(n0 + l16) * 256 + lk;
    __shared__ float wr[9][64];
    if (z == 0) {
        for (int i = t; i < 576; i += 256) wr[i >> 6][i & 63] = w_rpr[i];
    }
    f32x4 acc[4];
    f32x4 z4 = {0.f, 0.f, 0.f, 0.f};
    #pragma unroll
    for (int c = 0; c < 4; c++) acc[c] = z4;
    #pragma unroll
    for (int kk = 0; kk < 8; kk++) {
        bf16x8 av = *(const bf16x8*)(Ab + kk * 32);
        #pragma unroll
        for (int c = 0; c < 4; c++) {
            bf16x8 bv = *(const bf16x8*)(Wb + (size_t)c * 16 * 256 + kk * 32);
            acc[c] = mfma16(av, bv, acc[c]);
        }
    }
    int b = m0 >> 11;
    if (z == 0) {
        __syncthreads();
        #pragma unroll
        for (int r = 0; r < 4; r++) {
            float tv[9];
            #pragma unroll
            for (int p = 0; p < 9; p++) {
                float v = acc[0][r] * wr[p][l16] + acc[1][r] * wr[p][16 + l16]
                        + acc[2][r] * wr[p][32 + l16] + acc[3][r] * wr[p][48 + l16];
                v += __shfl_xor(v, 1); v += __shfl_xor(v, 2);
                v += __shfl_xor(v, 4); v += __shfl_xor(v, 8);
                tv[p] = __expf(v * 0.125f);
            }
            if (l16 == 0) {
                unsigned lo = __builtin_amdgcn_cvt_pk_fp8_f32(tv[0], tv[1], 0, false);
                lo = (unsigned)__builtin_amdgcn_cvt_pk_fp8_f32(tv[2], tv[3], (int)lo, true);
                unsigned hi = __builtin_amdgcn_cvt_pk_fp8_f32(tv[4], tv[5], 0, false);
                hi = (unsigned)__builtin_amdgcn_cvt_pk_fp8_f32(tv[6], tv[7], (int)hi, true);
                uint4 o;
                o.x = lo; o.y = hi;
                o.z = (unsigned)__float_as_int(tv[8]);
                o.w = 0u;
                qdrT8[(size_t)(mw + g * 4 + r) * NH + h] = o;
            }
        }
        __shared__ unsigned char ftq[64][80];
        #pragma unroll
        for (int c = 0; c < 4; c++)
            #pragma unroll
            for (int r = 0; r < 4; r++)
                ftq[wv_ * 16 + g * 4 + r][c * 16 + l16] = f2fp8(acc[c][r]);
        __syncthreads();
        int row = t >> 2, colq = (t & 3) * 16;
        uint4 v = *(const uint4*)&ftq[row][colq];
        *(uint4*)&qf8[(size_t)(m0 + row) * 256 + n0 + colq] = v;
    } else if (z == 1) {
        __shared__ unsigned char ft[64][80];
        #pragma unroll
        for (int c = 0; c < 4; c++)
            #pragma unroll
            for (int r = 0; r < 4; r++)
                ft[wv_ * 16 + g * 4 + r][c * 16 + l16] = f2fp8(acc[c][r]);
        __syncthreads();
        int rb_local = t >> 6;
        size_t rbase = ((size_t)(b * NH + h) * 128 + ((m0 & (NE - 1)) >> 4) + rb_local) * 1024;
        *(long long*)&kp8[rbase + l16 * 32 + g * 8] =
            *(const long long*)&ft[rb_local * 16 + l16][g * 8];
        *(long long*)&kp8[rbase + 512 + l16 * 32 + g * 8] =
            *(const long long*)&ft[rb_local * 16 + l16][32 + g * 8];
    } else {
        __shared__ unsigned char vt[64][72];
        #pragma unroll
        for (int c = 0; c < 4; c++)
            #pragma unroll
            for (int r = 0; r < 4; r++)
                vt[c * 16 + l16][wv_ * 16 + g * 4 + r] = f2fp8(acc[c][r]);
        __syncthreads();
        int eblk = (m0 & (NE - 1)) >> 6;
        size_t vbase = ((size_t)(b * NH + h) * 32 + eblk) * 4096;
        int dvb = t >> 7, sub = t & 127;
        int kk = sub >> 6, ln = sub & 63;
        int vl16 = ln & 15, vg = ln >> 4;
        #pragma unroll
        for (int dd = 0; dd < 2; dd++) {
            int dvblk = dvb + dd * 2;
            *(long long*)&vp8[vbase + (dvblk * 2 + kk) * 512 + vl16 * 32 + vg * 8] =
                *(const long long*)&vt[dvblk * 16 + vl16][kk * 32 + vg * 8];
        }
    }
}

// ---------------- fused attention, single merged QK+PV loop ------------------
// grid (NE/16, NB*NH), block 512 (8 waves). Wave ph owns tiles n0=(ph+8j)*64.
// Per j: V-loads issued first, QK^T -> exp -> P-LDS (unsigned stores), then PV
// MFMA reads the wave's own P bytes as UNSIGNED pairs (same TBAA type as the
// stores) after a compiler memory fence — wave-synchronous, no barrier.
__global__ __launch_bounds__(512, 4) void k_attn(
        const unsigned char* __restrict__ qf8, const unsigned char* __restrict__ kp8,
        const unsigned char* __restrict__ d8p, const uint4* __restrict__ qdrT8,
        const unsigned char* __restrict__ vp8, float* __restrict__ a_out,
        short* __restrict__ oatb) {
    __shared__ __align__(16) unsigned char P[16][PSTR8];  // 33.0 KB fp8
    __shared__ float comb[8][16];
    __shared__ float inv_lds[16];

    int t = threadIdx.x;
    int ph = t >> 6, lane = t & 63;
    int l16 = lane & 15, g = lane >> 4;
    int bh = blockIdx.y, b = bh >> 2, h = bh & 3;
    int m0 = blockIdx.x * 16;
    int lane32 = l16 * 32 + g * 8;
    int lane4 = (g * 16 + l16) * 4;

    uint4 tw = qdrT8[(size_t)(b * NE + m0 + l16) * NH + h];
    unsigned Tlo = tw.x, Thi = tw.y;
    float T8f = __int_as_float((int)tw.z);

    const unsigned char* Qb = qf8 + (size_t)(b * NE + m0 + l16) * 256 + h * 64 + g * 8;
    long long aq0 = *(const long long*)(Qb);
    long long aq1 = *(const long long*)(Qb + 32);

    const unsigned char* Kp = kp8 + (size_t)(b * NH + h) * 131072;
    const unsigned char* Vp = vp8 + (size_t)(b * NH + h) * 131072;
    const unsigned char* Dp = d8p + (size_t)(b * 128 + (m0 >> 4)) * 32768;

    float rs = 0.f;
    f32x4 accp[4];
    {
        f32x4 z4 = {0.f, 0.f, 0.f, 0.f};
        #pragma unroll
        for (int c = 0; c < 4; c++) accp[c] = z4;
    }

    // ---------------- merged pass: QK^T -> exp -> P, then PV (same j) ---------
    unsigned selc[4], seln[4];
    #pragma unroll
    for (int c = 0; c < 4; c++)
        selc[c] = *(const unsigned*)&Dp[ph * 1024 + c * 256 + lane4];
    #pragma unroll 1
    for (int j = 0; j < 4; j++) {
        int n0blk = ph + 8 * j;
        int n0 = n0blk * 64;
        // V loads for this j issued first — latency hides under QK compute
        long long vb0[4], vb1[4];
        #pragma unroll
        for (int c = 0; c < 4; c++) {
            const unsigned char* Vb = Vp + (size_t)n0blk * 4096 + (c * 2) * 512 + lane32;
            vb0[c] = *(const long long*)(Vb);
            vb1[c] = *(const long long*)(Vb + 512);
        }
        if (j < 3) {
            #pragma unroll
            for (int c = 0; c < 4; c++)
                seln[c] = *(const unsigned*)&Dp[(n0blk + 8) * 1024 + c * 256 + lane4];
        }
        #pragma unroll
        for (int c = 0; c < 4; c++) {
            const unsigned char* Bb = Kp + (size_t)(n0blk * 4 + c) * 1024 + lane32;
            long long kv0 = *(const long long*)(Bb);
            long long kv1 = *(const long long*)(Bb + 512);
            f32x4 acc = {0.f, 0.f, 0.f, 0.f};
            acc = mfma8(kv0, aq0, acc);
            acc = mfma8(kv1, aq1, acc);
            int kbase = n0 + c * 16 + g * 4;
            unsigned sel = selc[c];
            unsigned tpk = __builtin_amdgcn_perm(Thi, Tlo, sel);
            float tf0 = __builtin_amdgcn_cvt_f32_fp8((int)tpk, 0);
            float tf1 = __builtin_amdgcn_cvt_f32_fp8((int)tpk, 1);
            float tf2 = __builtin_amdgcn_cvt_f32_fp8((int)tpk, 2);
            float tf3 = __builtin_amdgcn_cvt_f32_fp8((int)tpk, 3);
            unsigned db0 = sel & 0xFFu;
            unsigned db1 = (sel >> 8) & 0xFFu;
            unsigned db2 = (sel >> 16) & 0xFFu;
            unsigned db3 = (sel >> 24) & 0xFFu;
            tf0 = db0 < 8 ? tf0 : (db0 == 8 ? T8f : 0.f);
            tf1 = db1 < 8 ? tf1 : (db1 == 8 ? T8f : 0.f);
            tf2 = db2 < 8 ? tf2 : (db2 == 8 ? T8f : 0.f);
            tf3 = db3 < 8 ? tf3 : (db3 == 8 ? T8f : 0.f);
            float e0 = __expf(acc[0] * 0.125f) * tf0;
            float e1 = __expf(acc[1] * 0.125f) * tf1;
            float e2 = __expf(acc[2] * 0.125f) * tf2;
            float e3 = __expf(acc[3] * 0.125f) * tf3;
            rs += (e0 + e1) + (e2 + e3);
            unsigned u = __builtin_amdgcn_cvt_pk_fp8_f32(e0, e1, 0, false);
            u = (unsigned)__builtin_amdgcn_cvt_pk_fp8_f32(e2, e3, (int)u, true);
            *(unsigned*)&P[l16][kbase] = u;
        }
        // fence: keep the unsigned P-stores ordered before the P-reads below
        __asm__ __volatile__("" ::: "memory");
        // PV from wave-local P (read as unsigned pairs — same type as stores)
        unsigned p0 = *(const unsigned*)&P[l16][n0 + g * 8];
        unsigned p1 = *(const unsigned*)&P[l16][n0 + g * 8 + 4];
        unsigned p2 = *(const unsigned*)&P[l16][n0 + 32 + g * 8];
        unsigned p3 = *(const unsigned*)&P[l16][n0 + 32 + g * 8 + 4];
        long long pa0 = (long long)(((unsigned long long)p1 << 32) | p0);
        long long pa1 = (long long)(((unsigned long long)p3 << 32) | p2);
        #pragma unroll
        for (int c = 0; c < 4; c++) {
            accp[c] = mfma8(pa0, vb0[c], accp[c]);
            accp[c] = mfma8(pa1, vb1[c], accp[c]);
        }
        if (j < 3) {
            #pragma unroll
            for (int c = 0; c < 4; c++) selc[c] = seln[c];
        }
    }
    rs += __shfl_xor(rs, 16);
    rs += __shfl_xor(rs, 32);
    if (lane < 16) comb[ph][l16] = rs;
    __syncthreads();
    if (t < 16) {
        float s = 0.f;
        #pragma unroll
        for (int w = 0; w < 8; w++) s += comb[w][t];
        inv_lds[t] = 1.0f / s;
    }
    __syncthreads();

    // ---------------- streaming a_out normalize + store -----------------------
    #pragma unroll 1
    for (int j = 0; j < 4; j++) {
        int n0 = (ph + 8 * j) * 64;
        #pragma unroll
        for (int r4 = 0; r4 < 4; r4++) {
            int row = r4 * 4 + g;
            unsigned u = *(const unsigned*)&P[row][n0 + l16 * 4];
            float iv = inv_lds[row];
            f32x4 o;
            o[0] = __builtin_amdgcn_cvt_f32_fp8((int)u, 0) * iv;
            o[1] = __builtin_amdgcn_cvt_f32_fp8((int)u, 1) * iv;
            o[2] = __builtin_amdgcn_cvt_f32_fp8((int)u, 2) * iv;
            o[3] = __builtin_amdgcn_cvt_f32_fp8((int)u, 3) * iv;
            *(f32x4*)&a_out[((size_t)bh * NE + m0 + row) * NE + n0 + l16 * 4] = o;
        }
    }

    // ---------------- combine PV partials across 8 waves (alias P) ------------
    __syncthreads();
    float (*pvcomb)[16][64] = (float (*)[16][64])&P[0][0];
    if (ph > 0) {
        #pragma unroll
        for (int c = 0; c < 4; c++)
            #pragma unroll
            for (int r = 0; r < 4; r++)
                pvcomb[ph - 1][g * 4 + r][c * 16 + l16] = accp[c][r];
    }
    __syncthreads();
    if (ph == 0) {
        #pragma unroll
        for (int c = 0; c < 4; c++) {
            #pragma unroll
            for (int r = 0; r < 4; r++) {
                float v = accp[c][r];
                #pragma unroll
                for (int w = 0; w < 7; w++) v += pvcomb[w][g * 4 + r][c * 16 + l16];
                v *= inv_lds[g * 4 + r];
                oatb[(size_t)(b * NE + m0 + g * 4 + r) * 256 + h * 64 + c * 16 + l16] = f2b(v);
            }
        }
    }
}

// ---------------- fc GEMM + residual from x + transposed store ----------------
__global__ __launch_bounds__(256) void k_gemm_fc(const short* __restrict__ A,
        const short* __restrict__ W, const float* __restrict__ x,
        float* __restrict__ xout) {
    int t = threadIdx.x;
    int wv_ = t >> 6, lane = t & 63;
    int l16 = lane & 15, g = lane >> 4, lk = g * 8;
    int m0 = blockIdx.x * 64, n0 = blockIdx.y * 64;
    int mw = m0 + wv_ * 16;
    const short* Ab = A + (size_t)(mw + l16) * 256 + lk;
    const short* Wb = W + (size_t)(n0 + l16) * 256 + lk;
    f32x4 acc[4];
    f32x4 z4 = {0.f, 0.f, 0.f, 0.f};
    #pragma unroll
    for (int c = 0; c < 4; c++) acc[c] = z4;
    #pragma unroll
    for (int kk = 0; kk < 8; kk++) {
        bf16x8 av = *(const bf16x8*)(Ab + kk * 32);
        #pragma unroll
        for (int c = 0; c < 4; c++) {
            bf16x8 bv = *(const bf16x8*)(Wb + (size_t)c * 16 * 256 + kk * 32);
            acc[c] = mfma16(av, bv, acc[c]);
        }
    }
    __shared__ float tl[64][68];
    #pragma unroll
    for (int c = 0; c < 4; c++)
        #pragma unroll
        for (int r = 0; r < 4; r++)
            tl[c * 16 + l16][wv_ * 16 + g * 4 + r] = acc[c][r];
    __syncthreads();
    int b = m0 >> 11, e0 = m0 & (NE - 1);
    int dl = t >> 2, ec = (t & 3) * 16;
    #pragma unroll
    for (int i = 0; i < 4; i++) {
        size_t idx = ((size_t)b * ND + n0 + dl) * NE + e0 + ec + i * 4;
        f32x4 xv = *(const f32x4*)&x[idx];
        f32x4 v = *(f32x4*)&tl[dl][ec + i * 4];
        v[0] += xv[0]; v[1] += xv[1]; v[2] += xv[2]; v[3] += xv[3];
        *(f32x4*)&xout[idx] = v;
    }
}

extern "C" void kernel_launch(void* const* d_in, const int* in_sizes, int n_in,
                              void* d_out, int out_size, void* d_ws, size_t ws_size,
                              hipStream_t stream) {
    const float* x    = (const float*)d_in[0];
    const int*   dist = (const int*)d_in[1];
    const float* w_qs = (const float*)d_in[2];
    const float* w_ks = (const float*)d_in[3];
    const float* w_vs = (const float*)d_in[4];
    const float* w_fc = (const float*)d_in[5];
    const float* w_rpr= (const float*)d_in[6];
    const float* ln_g = (const float*)d_in[7];
    const float* ln_b = (const float*)d_in[8];

    char* ws = (char*)d_ws;
    short* sbf  = (short*)(ws);                            // 2 MB
    short* qnb  = (short*)(ws + (2u  << 20));              // 2 MB
    unsigned char* qf8  = (unsigned char*)(ws + (4u << 20));   // 1 MB
    unsigned char* kp8  = (unsigned char*)(ws + (5u << 20));   // 1 MB
    unsigned char* vp8  = (unsigned char*)(ws + (6u << 20));   // 1 MB
    short* oatb = (short*)(ws + (7u  << 20));              // 2 MB
    uint4* qdrT8 = (uint4*)(ws + (9u << 20));              // 256 KB
    unsigned char* d8p = (unsigned char*)(ws + (10u << 20)); // 8.4 MB
    short* wqsb = (short*)(ws + (19u << 20));
    short* wksb = (short*)(ws + (19u << 20) + 131072);
    short* wvsb = (short*)(ws + (19u << 20) + 262144);
    short* wfcb = (short*)(ws + (19u << 20) + 393216);

    float* xout  = (float*)d_out;
    float* a_out = xout + (size_t)NB * ND * NE;

    k_front<<<dim3(448), dim3(512), 0, stream>>>(dist, d8p,
            w_qs, w_ks, w_vs, w_fc, wqsb, wksb, wvsb, wfcb,
            x, ln_g, ln_b, sbf, qnb);
    k_gemm_qkv<<<dim3(64, 4, 3), dim3(256), 0, stream>>>(qnb, sbf, wqsb, wksb, wvsb,
                                                         w_rpr, qf8, kp8, vp8, qdrT8);
    k_attn<<<dim3(NE / 16, NB * NH), dim3(512), 0, stream>>>(qf8, kp8, d8p, qdrT8,
                                                             vp8, a_out, oatb);
    k_gemm_fc<<<dim3(64, 4), dim3(256), 0, stream>>>(oatb, wfcb, x, xout);
}